// Round 4
// baseline (164.108 us; speedup 1.0000x reference)
//
#include <hip/hip_runtime.h>

#define SE_C   256
#define SE_B   16
#define SE_HW  16384   // 128*128

typedef float fx4 __attribute__((ext_vector_type(4)));   // native vector for nt builtins

// ---------------- Kernel 1: global average pool per (b,c) plane ----------------
__global__ __launch_bounds__(256) void se_pool(const float* __restrict__ U,
                                               float* __restrict__ z) {
    const int plane = blockIdx.x;                       // 0 .. B*C-1
    const fx4* Up = (const fx4*)(U + (size_t)plane * SE_HW);
    const int t = threadIdx.x;

    float sum = 0.f;
    #pragma unroll
    for (int k = 0; k < 16; ++k) {                      // 16 * 256 * 4 = 16384 floats
        fx4 v = Up[t + k * 256];
        sum += (v.x + v.y) + (v.z + v.w);
    }
    // wave (64-lane) shuffle reduce
    #pragma unroll
    for (int off = 32; off > 0; off >>= 1)
        sum += __shfl_down(sum, off, 64);

    __shared__ float wsum[4];
    const int lane = t & 63, wid = t >> 6;
    if (lane == 0) wsum[wid] = sum;
    __syncthreads();
    if (t == 0) {
        float tot = (wsum[0] + wsum[1]) + (wsum[2] + wsum[3]);
        z[plane] = tot * (1.0f / SE_HW);
    }
}

// ---------------- Kernel 2 (fused): per-plane gate compute + scale ----------------
// One block per (b,c) plane. Block redundantly computes its own gate:
//   h = relu(w_sq @ z[b,:])  (128 threads, one row each; w_sq hits L2)
//   g = sigmoid(w_ex[c,:] . h)  (all threads redundantly; h broadcast from LDS)
// First half of the plane is prefetched into VGPRs before the fc phase so the
// gate math overlaps load latency. Output uses nt-stores (keep U resident in L3).
__global__ __launch_bounds__(256) void se_scale_fc(const float* __restrict__ U,
                                                   const float* __restrict__ z,
                                                   const float* __restrict__ w_sq,  // [128,256]
                                                   const float* __restrict__ w_ex,  // [256,128]
                                                   float* __restrict__ out) {
    const int plane = blockIdx.x;
    const int b = plane >> 8;
    const int c = plane & 255;
    const int t = threadIdx.x;

    const fx4* Up = (const fx4*)(U + (size_t)plane * SE_HW);
    fx4* Op = (fx4*)(out + (size_t)plane * SE_HW);

    // Prefetch first half of the plane (8 fx4 = 32 VGPRs) — hides fc latency.
    fx4 pre[8];
    #pragma unroll
    for (int k = 0; k < 8; ++k) pre[k] = Up[t + k * 256];

    __shared__ float zb[SE_C];
    __shared__ float h[SE_C / 2];

    zb[t] = z[b * SE_C + t];
    __syncthreads();

    if (t < SE_C / 2) {
        const float* wr = w_sq + t * SE_C;
        float acc = 0.f;
        #pragma unroll 8
        for (int k = 0; k < SE_C; ++k) acc = fmaf(wr[k], zb[k], acc);
        h[t] = fmaxf(acc, 0.f);
    }
    __syncthreads();

    const float* we = w_ex + c * (SE_C / 2);
    float acc = 0.f;
    #pragma unroll 8
    for (int k = 0; k < SE_C / 2; ++k) acc = fmaf(we[k], h[k], acc);
    const float g = 1.0f / (1.0f + __expf(-acc));

    #pragma unroll
    for (int k = 0; k < 8; ++k) {
        fx4 v = pre[k] * g;
        __builtin_nontemporal_store(v, Op + t + k * 256);
    }
    #pragma unroll
    for (int k = 8; k < 16; ++k) {
        fx4 v = Up[t + k * 256] * g;
        __builtin_nontemporal_store(v, Op + t + k * 256);
    }
}

extern "C" void kernel_launch(void* const* d_in, const int* in_sizes, int n_in,
                              void* d_out, int out_size, void* d_ws, size_t ws_size,
                              hipStream_t stream) {
    const float* U    = (const float*)d_in[0];
    const float* w_sq = (const float*)d_in[1];
    const float* w_ex = (const float*)d_in[2];
    float* out = (float*)d_out;

    float* z = (float*)d_ws;             // [B*C] = 4096 floats

    se_pool<<<SE_B * SE_C, 256, 0, stream>>>(U, z);
    se_scale_fc<<<SE_B * SE_C, 256, 0, stream>>>(U, z, w_sq, w_ex, out);
}